// Round 9
// baseline (1322.366 us; speedup 1.0000x reference)
//
#include <hip/hip_runtime.h>
#include <stdint.h>

using ushort8 = __attribute__((ext_vector_type(8))) unsigned short;
using bf16x8  = __attribute__((ext_vector_type(8))) __bf16;
using f32x16  = __attribute__((ext_vector_type(16))) float;
using u32x4   = __attribute__((ext_vector_type(4))) uint32_t;
using us4     = __attribute__((ext_vector_type(4))) unsigned short;

__device__ __forceinline__ unsigned short f2bf(float x){
  uint32_t u = __builtin_bit_cast(uint32_t, x);
  u = (u + 0x7FFFu + ((u >> 16) & 1u)) >> 16;   // RNE
  return (unsigned short)u;
}
__device__ __forceinline__ float bf2f(unsigned short b){
  uint32_t u = ((uint32_t)b) << 16;
  return __builtin_bit_cast(float, u);
}

__device__ __forceinline__ f32x16 mfma16(bf16x8 a, bf16x8 b, f32x16 c){
  return __builtin_amdgcn_mfma_f32_32x32x16_bf16(a, b, c, 0, 0, 0);
}

__device__ __forceinline__ bf16x8 cvt8(const float* p){
  ushort8 v;
  #pragma unroll
  for (int j = 0; j < 8; ++j) v[j] = f2bf(p[j]);
  return __builtin_bit_cast(bf16x8, v);
}

// Pre-pass (unchanged, verified): Wb4[s][slice(pt,ch)][granule q][8 bf16].
// Granule q = cc*64 + lg*32 + l31 holds A-frag chunk for lane (l31,lg), frag cc:
//   p = pt*32 + l31, c = ch*64 + cc*16 + lg*8 + j.
// s<128: A[p][c] = W[(s*128+p)*128+c]; s=128: A[p][i] = b[i*128+p].
__global__ void prep_wb4(const float* __restrict__ W, const float* __restrict__ bias,
                         unsigned short* __restrict__ Wb4){
  int e = blockIdx.x * 256 + threadIdx.x;
  if (e >= 129 * 16384) return;
  int jj = e & 7, q = (e >> 3) & 255, sl = (e >> 11) & 7, s = e >> 14;
  int ch = sl & 1, pt = sl >> 1;
  int cc = q >> 6, lg = (q >> 5) & 1, l31 = q & 31;
  int p = pt * 32 + l31;
  int c = ch * 64 + cc * 16 + lg * 8 + jj;
  float v = (s < 128) ? W[(s << 14) + (p << 7) + c] : bias[(c << 7) + p];
  Wb4[e] = f2bf(v);
}

// dynmlp: grid 512 = 128 token-tiles x 4 K-quarters (tt=b>>2, hq=b&3).
// Round-robin XCD assignment => XCD x serves only quarter x&3 (1MB L2 set).
// 2 WGs/CU (launch_bounds(512,4)): 16 waves/CU, 4/SIMD -- the occupancy fix.
// 512 thr = 8 waves = 4 pt x 2 ch; wave tile 32p x 128t (F=4) x 64c; 32 steps.
// A-fragments global->register, depth-3 banks (static), per-wave rotation.
// Tail: plain C++ acc[f] += T*s (packed FMA, no asm movs).
// LDS: imgT 8KB (union with 66KB ldsY used only in epilogue).
__global__ __launch_bounds__(512, 4)
void dynmlp(const float* __restrict__ img, const float* __restrict__ loc,
            const unsigned short* __restrict__ Wb4, unsigned short* __restrict__ part){
  __shared__ __align__(16) char smem[66048];
  unsigned short* imgT = (unsigned short*)smem;   // [32 s][slot(t)] u16, 8KB
  float* ldsY = (float*)smem;                     // [128 t][129 p] f32 (epilogue)

  const int b = blockIdx.x;
  const int tt = b >> 2, hq = b & 3;
  const int tid = threadIdx.x, lane = tid & 63, wv = tid >> 6;
  const int pt = wv >> 1, ch = wv & 1;
  const int l31 = lane & 31, lg = lane >> 5;
  const int t0 = tt * 128;
  const int rot = wv << 2;                        // per-wave step rotation (stride 4 over 32)

  const char* wlane = (const char*)Wb4 +
      ((size_t)(hq * 32) * 8 + (size_t)(pt * 2 + ch)) * 4096 + (lane << 4);
  const char* blane = (const char*)Wb4 +
      ((size_t)128 * 8 + (size_t)(pt * 2 + ch)) * 4096 + (lane << 4);

  // ---- imgT fill: rows s=0..31 (i = hq*32+s); slot(t) = (t&31)*4 + (t>>5) ----
  for (int e = tid; e < 1024; e += 512){
    int tl = e & 127, iq = e >> 7;               // iq = 0..7
    float4 v = *(const float4*)&img[(size_t)(t0 + tl) * 128 + hq * 32 + iq * 4];
    int slot = (tl & 31) * 4 + (tl >> 5);
    imgT[(iq * 4 + 0) * 128 + slot] = f2bf(v.x);
    imgT[(iq * 4 + 1) * 128 + slot] = f2bf(v.y);
    imgT[(iq * 4 + 2) * 128 + slot] = f2bf(v.z);
    imgT[(iq * 4 + 3) * 128 + slot] = f2bf(v.w);
  }

  // ---- register-stationary B-frags (loc, this wave's c-half) ----
  bf16x8 bfr[4][4];
  #pragma unroll
  for (int f = 0; f < 4; ++f){
    int t = t0 + f * 32 + l31;
    #pragma unroll
    for (int cc = 0; cc < 4; ++cc)
      bfr[f][cc] = cvt8(&loc[(size_t)t * 128 + ch * 64 + cc * 16 + lg * 8]);
  }

  // persistent zero C-operand (asm-pinned so it is materialized ONCE)
  f32x16 Z;
  #pragma unroll
  for (int i = 0; i < 16; ++i) Z[i] = 0.0f;
  asm volatile("" : "+v"(Z));

  f32x16 acc[4];
  #pragma unroll
  for (int f = 0; f < 4; ++f) acc[f] = Z;

  #define LP(K) (((K) + rot) & 31)
  #define LOADB(BK, STEP) do { \
    const u32x4* _g = (const u32x4*)(wlane + (size_t)LP(STEP) * 32768); \
    BK[0] = _g[0]; BK[1] = _g[64]; BK[2] = _g[128]; BK[3] = _g[192]; \
  } while (0)

  // ---- depth-3 prologue ----
  u32x4 b0[4], b1[4], b2[4];
  LOADB(b0, 0); LOADB(b1, 1); LOADB(b2, 2);

  __syncthreads();                     // imgT ready

  const unsigned short* imgP = imgT + l31 * 4;

  // body: two MFMA clusters of 2 chains; plain C++ scaled accumulate (packed FMA)
  #define STEPBODY(AV, W4) do { \
    bf16x8 a0 = __builtin_bit_cast(bf16x8, AV[0]); \
    bf16x8 a1 = __builtin_bit_cast(bf16x8, AV[1]); \
    bf16x8 a2 = __builtin_bit_cast(bf16x8, AV[2]); \
    bf16x8 a3 = __builtin_bit_cast(bf16x8, AV[3]); \
    float s0 = bf2f(W4[0]), s1 = bf2f(W4[1]), s2 = bf2f(W4[2]), s3 = bf2f(W4[3]); \
    __builtin_amdgcn_s_setprio(1); \
    f32x16 T0 = mfma16(a0, bfr[0][0], Z); \
    f32x16 T1 = mfma16(a0, bfr[1][0], Z); \
    T0 = mfma16(a1, bfr[0][1], T0); T1 = mfma16(a1, bfr[1][1], T1); \
    T0 = mfma16(a2, bfr[0][2], T0); T1 = mfma16(a2, bfr[1][2], T1); \
    T0 = mfma16(a3, bfr[0][3], T0); T1 = mfma16(a3, bfr[1][3], T1); \
    __builtin_amdgcn_s_setprio(0); \
    acc[0] += T0 * s0; acc[1] += T1 * s1; \
    __builtin_amdgcn_s_setprio(1); \
    f32x16 U0 = mfma16(a0, bfr[2][0], Z); \
    f32x16 U1 = mfma16(a0, bfr[3][0], Z); \
    U0 = mfma16(a1, bfr[2][1], U0); U1 = mfma16(a1, bfr[3][1], U1); \
    U0 = mfma16(a2, bfr[2][2], U0); U1 = mfma16(a2, bfr[3][2], U1); \
    U0 = mfma16(a3, bfr[2][3], U0); U1 = mfma16(a3, bfr[3][3], U1); \
    __builtin_amdgcn_s_setprio(0); \
    acc[2] += U0 * s2; acc[3] += U1 * s3; \
  } while (0)

  // ---- main loop: k = 0,3,...,24: bodies k..k+2, loads k+3..k+5 ----
  for (int k = 0; k < 27; k += 3){
    us4 w;
    w = *(const us4*)(imgP + LP(k + 0) * 128); STEPBODY(b0, w); LOADB(b0, k + 3);
    w = *(const us4*)(imgP + LP(k + 1) * 128); STEPBODY(b1, w); LOADB(b1, k + 4);
    w = *(const us4*)(imgP + LP(k + 2) * 128); STEPBODY(b2, w); LOADB(b2, k + 5);
  }
  // ---- tail: bodies 27..31; bias prefetch (hq==0) into b2 ----
  {
    us4 w;
    w = *(const us4*)(imgP + LP(27) * 128); STEPBODY(b0, w); LOADB(b0, 30);
    w = *(const us4*)(imgP + LP(28) * 128); STEPBODY(b1, w); LOADB(b1, 31);
    w = *(const us4*)(imgP + LP(29) * 128); STEPBODY(b2, w);
    if (hq == 0){
      const u32x4* _g = (const u32x4*)blane;
      b2[0] = _g[0]; b2[1] = _g[64]; b2[2] = _g[128]; b2[3] = _g[192];
    }
    w = *(const us4*)(imgP + LP(30) * 128); STEPBODY(b0, w);
    w = *(const us4*)(imgP + LP(31) * 128); STEPBODY(b1, w);
  }

  // ---- bias step (hq==0): acc += A_bias x img-frags (K-dim = i, via ch split) ----
  if (hq == 0){
    bf16x8 a0 = __builtin_bit_cast(bf16x8, b2[0]);
    bf16x8 a1 = __builtin_bit_cast(bf16x8, b2[1]);
    bf16x8 a2 = __builtin_bit_cast(bf16x8, b2[2]);
    bf16x8 a3 = __builtin_bit_cast(bf16x8, b2[3]);
    #pragma unroll
    for (int f = 0; f < 4; ++f){
      size_t tr = (size_t)(t0 + f * 32 + l31) * 128 + ch * 64 + lg * 8;
      f32x16 T = mfma16(a0, cvt8(&img[tr]),      Z);
      T = mfma16(a1, cvt8(&img[tr + 16]), T);
      T = mfma16(a2, cvt8(&img[tr + 32]), T);
      T = mfma16(a3, cvt8(&img[tr + 48]), T);
      acc[f] += T;
    }
  }

  // ---- epilogue: combine c-halves in LDS, write bf16 partial coalesced ----
  // C/D layout: col = l31 (t), row r = (r&3) + 8*(r>>2) + 4*lg (p)
  __syncthreads();   // imgT dead; ldsY takes over
  if (ch == 0){
    #pragma unroll
    for (int f = 0; f < 4; ++f){
      int t_l = f * 32 + l31;
      #pragma unroll
      for (int r = 0; r < 16; ++r){
        int p = pt * 32 + (r & 3) + 8 * (r >> 2) + 4 * lg;
        ldsY[t_l * 129 + p] = acc[f][r];
      }
    }
  }
  __syncthreads();
  if (ch == 1){
    #pragma unroll
    for (int f = 0; f < 4; ++f){
      int t_l = f * 32 + l31;
      #pragma unroll
      for (int r = 0; r < 16; ++r){
        int p = pt * 32 + (r & 3) + 8 * (r >> 2) + 4 * lg;
        ldsY[t_l * 129 + p] += acc[f][r];
      }
    }
  }
  __syncthreads();
  unsigned short* dst = part + (size_t)hq * 16384 * 128 + (size_t)t0 * 128;
  #pragma unroll
  for (int k = 0; k < 8; ++k){
    int idx4 = k * 512 + tid;
    int t_l = idx4 >> 5, q = idx4 & 31;
    const float* s = &ldsY[t_l * 129 + q * 4];
    us4 v = {f2bf(s[0]), f2bf(s[1]), f2bf(s[2]), f2bf(s[3])};
    *(us4*)&dst[t_l * 128 + q * 4] = v;
  }
}

// LN kernel: y = sum of 4 bf16 partials, LayerNorm + ReLU. grid 256 x 512 thr.
__global__ __launch_bounds__(512)
void lnk(const unsigned short* __restrict__ part, const float* __restrict__ gamma,
         const float* __restrict__ beta, float* __restrict__ out){
  const int tid = threadIdx.x, lane = tid & 63, wv = tid >> 6;
  const unsigned short* p0 = part;
  const unsigned short* p1 = part + (size_t)16384 * 128;
  const unsigned short* p2 = part + (size_t)2 * 16384 * 128;
  const unsigned short* p3 = part + (size_t)3 * 16384 * 128;
  float g0  = gamma[lane], g1 = gamma[lane + 64];
  float be0 = beta[lane],  be1 = beta[lane + 64];
  int tb = blockIdx.x * 64 + wv * 8;
  #pragma unroll 1
  for (int k = 0; k < 8; ++k){
    size_t t = tb + k;
    size_t i0 = t * 128 + lane, i1 = i0 + 64;
    float y0 = bf2f(p0[i0]) + bf2f(p1[i0]) + bf2f(p2[i0]) + bf2f(p3[i0]);
    float y1 = bf2f(p0[i1]) + bf2f(p1[i1]) + bf2f(p2[i1]) + bf2f(p3[i1]);
    float s = y0 + y1, sq = y0 * y0 + y1 * y1;
    #pragma unroll
    for (int m = 32; m >= 1; m >>= 1){
      s  += __shfl_xor(s, m, 64);
      sq += __shfl_xor(sq, m, 64);
    }
    float mean = s * (1.0f / 128.0f);
    float var  = sq * (1.0f / 128.0f) - mean * mean;
    float rs   = rsqrtf(var + 1e-5f);
    float o0 = fmaxf((y0 - mean) * rs * g0 + be0, 0.0f);
    float o1 = fmaxf((y1 - mean) * rs * g1 + be1, 0.0f);
    out[t * 128 + lane]      = o0;
    out[t * 128 + 64 + lane] = o1;
  }
}

extern "C" void kernel_launch(void* const* d_in, const int* in_sizes, int n_in,
                              void* d_out, int out_size, void* d_ws, size_t ws_size,
                              hipStream_t stream){
  const float* img   = (const float*)d_in[0];
  const float* loc   = (const float*)d_in[1];
  const float* W     = (const float*)d_in[2];
  const float* bias  = (const float*)d_in[3];
  const float* gamma = (const float*)d_in[4];
  const float* beta  = (const float*)d_in[5];
  float* out = (float*)d_out;
  unsigned short* Wb4  = (unsigned short*)d_ws;                    // 4,227,072 B
  unsigned short* part = (unsigned short*)((char*)d_ws + 4227072); // 4 x 16384 x 128 bf16 = 16.78 MB

  prep_wb4<<<8256, 256, 0, stream>>>(W, bias, Wb4);
  dynmlp<<<512, 512, 0, stream>>>(img, loc, Wb4, part);
  lnk<<<256, 512, 0, stream>>>(part, gamma, beta, out);
}

// Round 10
// 175.135 us; speedup vs baseline: 7.5505x; 7.5505x over previous
//
#include <hip/hip_runtime.h>
#include <stdint.h>

using ushort8 = __attribute__((ext_vector_type(8))) unsigned short;
using bf16x8  = __attribute__((ext_vector_type(8))) __bf16;
using f32x16  = __attribute__((ext_vector_type(16))) float;
using u32x4   = __attribute__((ext_vector_type(4))) uint32_t;
using us4     = __attribute__((ext_vector_type(4))) unsigned short;

__device__ __forceinline__ unsigned short f2bf(float x){
  uint32_t u = __builtin_bit_cast(uint32_t, x);
  u = (u + 0x7FFFu + ((u >> 16) & 1u)) >> 16;   // RNE
  return (unsigned short)u;
}
__device__ __forceinline__ float bf2f(unsigned short b){
  uint32_t u = ((uint32_t)b) << 16;
  return __builtin_bit_cast(float, u);
}

__device__ __forceinline__ f32x16 mfma16(bf16x8 a, bf16x8 b, f32x16 c){
  return __builtin_amdgcn_mfma_f32_32x32x16_bf16(a, b, c, 0, 0, 0);
}

__device__ __forceinline__ bf16x8 cvt8(const float* p){
  ushort8 v;
  #pragma unroll
  for (int j = 0; j < 8; ++j) v[j] = f2bf(p[j]);
  return __builtin_bit_cast(bf16x8, v);
}

// Pre-pass (unchanged, verified): Wb4[s][slice(pt,ch)][granule q][8 bf16].
// Granule q = cc*64 + lg*32 + l31 holds A-frag chunk for lane (l31,lg), frag cc:
//   p = pt*32 + l31, c = ch*64 + cc*16 + lg*8 + j.
// s<128: A[p][c] = W[(s*128+p)*128+c]; s=128: A[p][i] = b[i*128+p].
__global__ void prep_wb4(const float* __restrict__ W, const float* __restrict__ bias,
                         unsigned short* __restrict__ Wb4){
  int e = blockIdx.x * 256 + threadIdx.x;
  if (e >= 129 * 16384) return;
  int jj = e & 7, q = (e >> 3) & 255, sl = (e >> 11) & 7, s = e >> 14;
  int ch = sl & 1, pt = sl >> 1;
  int cc = q >> 6, lg = (q >> 5) & 1, l31 = q & 31;
  int p = pt * 32 + l31;
  int c = ch * 64 + cc * 16 + lg * 8 + jj;
  float v = (s < 128) ? W[(s << 14) + (p << 7) + c] : bias[(c << 7) + p];
  Wb4[e] = f2bf(v);
}

// dynmlp: grid 512 = 128 token-tiles x 4 K-quarters (tt=b>>2, hq=b&3).
// Round-robin XCD assignment => XCD x serves only quarter x&3 (1MB L2 set).
// __launch_bounds__(512,2): empirically the 128-VGPR / no-spill point
// (r9's (512,4) capped VGPR at 64 -> total scratch spill, 2.4GB FETCH).
// Residency: VGPR 128 x 16 waves = 2048 ok, LDS 2x66KB = 132 <= 160KB ok
// -> 2 WGs/CU, 4 waves/SIMD (the occupancy experiment, now actually run).
// 512 thr = 8 waves = 4 pt x 2 ch; wave tile 32p x 128t (F=4) x 64c; 32 steps.
// A-fragments global->register, depth-3 banks (static), per-wave rotation.
// LDS: imgT 8KB (union with 66KB ldsY used only in epilogue).
__global__ __launch_bounds__(512, 2)
void dynmlp(const float* __restrict__ img, const float* __restrict__ loc,
            const unsigned short* __restrict__ Wb4, unsigned short* __restrict__ part){
  __shared__ __align__(16) char smem[66048];
  unsigned short* imgT = (unsigned short*)smem;   // [32 s][slot(t)] u16, 8KB
  float* ldsY = (float*)smem;                     // [128 t][129 p] f32 (epilogue)

  const int b = blockIdx.x;
  const int tt = b >> 2, hq = b & 3;
  const int tid = threadIdx.x, lane = tid & 63, wv = tid >> 6;
  const int pt = wv >> 1, ch = wv & 1;
  const int l31 = lane & 31, lg = lane >> 5;
  const int t0 = tt * 128;
  const int rot = wv << 2;                        // per-wave step rotation (stride 4 over 32)

  const char* wlane = (const char*)Wb4 +
      ((size_t)(hq * 32) * 8 + (size_t)(pt * 2 + ch)) * 4096 + (lane << 4);
  const char* blane = (const char*)Wb4 +
      ((size_t)128 * 8 + (size_t)(pt * 2 + ch)) * 4096 + (lane << 4);

  // ---- imgT fill: rows s=0..31 (i = hq*32+s); slot(t) = (t&31)*4 + (t>>5) ----
  for (int e = tid; e < 1024; e += 512){
    int tl = e & 127, iq = e >> 7;               // iq = 0..7
    float4 v = *(const float4*)&img[(size_t)(t0 + tl) * 128 + hq * 32 + iq * 4];
    int slot = (tl & 31) * 4 + (tl >> 5);
    imgT[(iq * 4 + 0) * 128 + slot] = f2bf(v.x);
    imgT[(iq * 4 + 1) * 128 + slot] = f2bf(v.y);
    imgT[(iq * 4 + 2) * 128 + slot] = f2bf(v.z);
    imgT[(iq * 4 + 3) * 128 + slot] = f2bf(v.w);
  }

  // ---- register-stationary B-frags (loc, this wave's c-half) ----
  bf16x8 bfr[4][4];
  #pragma unroll
  for (int f = 0; f < 4; ++f){
    int t = t0 + f * 32 + l31;
    #pragma unroll
    for (int cc = 0; cc < 4; ++cc)
      bfr[f][cc] = cvt8(&loc[(size_t)t * 128 + ch * 64 + cc * 16 + lg * 8]);
  }

  // persistent zero C-operand (asm-pinned so it is materialized ONCE)
  f32x16 Z;
  #pragma unroll
  for (int i = 0; i < 16; ++i) Z[i] = 0.0f;
  asm volatile("" : "+v"(Z));

  f32x16 acc[4];
  #pragma unroll
  for (int f = 0; f < 4; ++f) acc[f] = Z;

  #define LP(K) (((K) + rot) & 31)
  #define LOADB(BK, STEP) do { \
    const u32x4* _g = (const u32x4*)(wlane + (size_t)LP(STEP) * 32768); \
    BK[0] = _g[0]; BK[1] = _g[64]; BK[2] = _g[128]; BK[3] = _g[192]; \
  } while (0)

  // ---- depth-3 prologue ----
  u32x4 b0[4], b1[4], b2[4];
  LOADB(b0, 0); LOADB(b1, 1); LOADB(b2, 2);

  __syncthreads();                     // imgT ready

  const unsigned short* imgP = imgT + l31 * 4;

  // body: two MFMA clusters of 2 chains; plain C++ scaled accumulate (packed FMA)
  #define STEPBODY(AV, W4) do { \
    bf16x8 a0 = __builtin_bit_cast(bf16x8, AV[0]); \
    bf16x8 a1 = __builtin_bit_cast(bf16x8, AV[1]); \
    bf16x8 a2 = __builtin_bit_cast(bf16x8, AV[2]); \
    bf16x8 a3 = __builtin_bit_cast(bf16x8, AV[3]); \
    float s0 = bf2f(W4[0]), s1 = bf2f(W4[1]), s2 = bf2f(W4[2]), s3 = bf2f(W4[3]); \
    __builtin_amdgcn_s_setprio(1); \
    f32x16 T0 = mfma16(a0, bfr[0][0], Z); \
    f32x16 T1 = mfma16(a0, bfr[1][0], Z); \
    T0 = mfma16(a1, bfr[0][1], T0); T1 = mfma16(a1, bfr[1][1], T1); \
    T0 = mfma16(a2, bfr[0][2], T0); T1 = mfma16(a2, bfr[1][2], T1); \
    T0 = mfma16(a3, bfr[0][3], T0); T1 = mfma16(a3, bfr[1][3], T1); \
    __builtin_amdgcn_s_setprio(0); \
    acc[0] += T0 * s0; acc[1] += T1 * s1; \
    __builtin_amdgcn_s_setprio(1); \
    f32x16 U0 = mfma16(a0, bfr[2][0], Z); \
    f32x16 U1 = mfma16(a0, bfr[3][0], Z); \
    U0 = mfma16(a1, bfr[2][1], U0); U1 = mfma16(a1, bfr[3][1], U1); \
    U0 = mfma16(a2, bfr[2][2], U0); U1 = mfma16(a2, bfr[3][2], U1); \
    U0 = mfma16(a3, bfr[2][3], U0); U1 = mfma16(a3, bfr[3][3], U1); \
    __builtin_amdgcn_s_setprio(0); \
    acc[2] += U0 * s2; acc[3] += U1 * s3; \
  } while (0)

  // ---- main loop: k = 0,3,...,24: bodies k..k+2, loads k+3..k+5 ----
  for (int k = 0; k < 27; k += 3){
    us4 w;
    w = *(const us4*)(imgP + LP(k + 0) * 128); STEPBODY(b0, w); LOADB(b0, k + 3);
    w = *(const us4*)(imgP + LP(k + 1) * 128); STEPBODY(b1, w); LOADB(b1, k + 4);
    w = *(const us4*)(imgP + LP(k + 2) * 128); STEPBODY(b2, w); LOADB(b2, k + 5);
  }
  // ---- tail: bodies 27..31; bias prefetch (hq==0) into b2 ----
  {
    us4 w;
    w = *(const us4*)(imgP + LP(27) * 128); STEPBODY(b0, w); LOADB(b0, 30);
    w = *(const us4*)(imgP + LP(28) * 128); STEPBODY(b1, w); LOADB(b1, 31);
    w = *(const us4*)(imgP + LP(29) * 128); STEPBODY(b2, w);
    if (hq == 0){
      const u32x4* _g = (const u32x4*)blane;
      b2[0] = _g[0]; b2[1] = _g[64]; b2[2] = _g[128]; b2[3] = _g[192];
    }
    w = *(const us4*)(imgP + LP(30) * 128); STEPBODY(b0, w);
    w = *(const us4*)(imgP + LP(31) * 128); STEPBODY(b1, w);
  }

  // ---- bias step (hq==0): acc += A_bias x img-frags ----
  if (hq == 0){
    bf16x8 a0 = __builtin_bit_cast(bf16x8, b2[0]);
    bf16x8 a1 = __builtin_bit_cast(bf16x8, b2[1]);
    bf16x8 a2 = __builtin_bit_cast(bf16x8, b2[2]);
    bf16x8 a3 = __builtin_bit_cast(bf16x8, b2[3]);
    #pragma unroll
    for (int f = 0; f < 4; ++f){
      size_t tr = (size_t)(t0 + f * 32 + l31) * 128 + ch * 64 + lg * 8;
      f32x16 T = mfma16(a0, cvt8(&img[tr]),      Z);
      T = mfma16(a1, cvt8(&img[tr + 16]), T);
      T = mfma16(a2, cvt8(&img[tr + 32]), T);
      T = mfma16(a3, cvt8(&img[tr + 48]), T);
      acc[f] += T;
    }
  }

  // ---- epilogue: combine c-halves in LDS, write bf16 partial coalesced ----
  // C/D layout: col = l31 (t), row r = (r&3) + 8*(r>>2) + 4*lg (p)
  __syncthreads();   // imgT dead; ldsY takes over
  if (ch == 0){
    #pragma unroll
    for (int f = 0; f < 4; ++f){
      int t_l = f * 32 + l31;
      #pragma unroll
      for (int r = 0; r < 16; ++r){
        int p = pt * 32 + (r & 3) + 8 * (r >> 2) + 4 * lg;
        ldsY[t_l * 129 + p] = acc[f][r];
      }
    }
  }
  __syncthreads();
  if (ch == 1){
    #pragma unroll
    for (int f = 0; f < 4; ++f){
      int t_l = f * 32 + l31;
      #pragma unroll
      for (int r = 0; r < 16; ++r){
        int p = pt * 32 + (r & 3) + 8 * (r >> 2) + 4 * lg;
        ldsY[t_l * 129 + p] += acc[f][r];
      }
    }
  }
  __syncthreads();
  unsigned short* dst = part + (size_t)hq * 16384 * 128 + (size_t)t0 * 128;
  #pragma unroll
  for (int k = 0; k < 8; ++k){
    int idx4 = k * 512 + tid;
    int t_l = idx4 >> 5, q = idx4 & 31;
    const float* s = &ldsY[t_l * 129 + q * 4];
    us4 v = {f2bf(s[0]), f2bf(s[1]), f2bf(s[2]), f2bf(s[3])};
    *(us4*)&dst[t_l * 128 + q * 4] = v;
  }
}

// LN kernel: y = sum of 4 bf16 partials, LayerNorm + ReLU. grid 256 x 512 thr.
__global__ __launch_bounds__(512)
void lnk(const unsigned short* __restrict__ part, const float* __restrict__ gamma,
         const float* __restrict__ beta, float* __restrict__ out){
  const int tid = threadIdx.x, lane = tid & 63, wv = tid >> 6;
  const unsigned short* p0 = part;
  const unsigned short* p1 = part + (size_t)16384 * 128;
  const unsigned short* p2 = part + (size_t)2 * 16384 * 128;
  const unsigned short* p3 = part + (size_t)3 * 16384 * 128;
  float g0  = gamma[lane], g1 = gamma[lane + 64];
  float be0 = beta[lane],  be1 = beta[lane + 64];
  int tb = blockIdx.x * 64 + wv * 8;
  #pragma unroll 1
  for (int k = 0; k < 8; ++k){
    size_t t = tb + k;
    size_t i0 = t * 128 + lane, i1 = i0 + 64;
    float y0 = bf2f(p0[i0]) + bf2f(p1[i0]) + bf2f(p2[i0]) + bf2f(p3[i0]);
    float y1 = bf2f(p0[i1]) + bf2f(p1[i1]) + bf2f(p2[i1]) + bf2f(p3[i1]);
    float s = y0 + y1, sq = y0 * y0 + y1 * y1;
    #pragma unroll
    for (int m = 32; m >= 1; m >>= 1){
      s  += __shfl_xor(s, m, 64);
      sq += __shfl_xor(sq, m, 64);
    }
    float mean = s * (1.0f / 128.0f);
    float var  = sq * (1.0f / 128.0f) - mean * mean;
    float rs   = rsqrtf(var + 1e-5f);
    float o0 = fmaxf((y0 - mean) * rs * g0 + be0, 0.0f);
    float o1 = fmaxf((y1 - mean) * rs * g1 + be1, 0.0f);
    out[t * 128 + lane]      = o0;
    out[t * 128 + 64 + lane] = o1;
  }
}

extern "C" void kernel_launch(void* const* d_in, const int* in_sizes, int n_in,
                              void* d_out, int out_size, void* d_ws, size_t ws_size,
                              hipStream_t stream){
  const float* img   = (const float*)d_in[0];
  const float* loc   = (const float*)d_in[1];
  const float* W     = (const float*)d_in[2];
  const float* bias  = (const float*)d_in[3];
  const float* gamma = (const float*)d_in[4];
  const float* beta  = (const float*)d_in[5];
  float* out = (float*)d_out;
  unsigned short* Wb4  = (unsigned short*)d_ws;                    // 4,227,072 B
  unsigned short* part = (unsigned short*)((char*)d_ws + 4227072); // 4 x 16384 x 128 bf16 = 16.78 MB

  prep_wb4<<<8256, 256, 0, stream>>>(W, bias, Wb4);
  dynmlp<<<512, 512, 0, stream>>>(img, loc, Wb4, part);
  lnk<<<256, 512, 0, stream>>>(part, gamma, beta, out);
}

// Round 11
// 111.041 us; speedup vs baseline: 11.9088x; 1.5772x over previous
//
#include <hip/hip_runtime.h>
#include <stdint.h>

using bf16x8  = __attribute__((ext_vector_type(8))) __bf16;
using f32x16  = __attribute__((ext_vector_type(16))) float;
using u32x4   = __attribute__((ext_vector_type(4))) uint32_t;
using us4     = __attribute__((ext_vector_type(4))) unsigned short;

#define AS1 __attribute__((address_space(1)))
#define AS3 __attribute__((address_space(3)))

__device__ __forceinline__ unsigned short f2bf(float x){
  uint32_t u = __builtin_bit_cast(uint32_t, x);
  u = (u + 0x7FFFu + ((u >> 16) & 1u)) >> 16;   // RNE
  return (unsigned short)u;
}
__device__ __forceinline__ float bf2f(unsigned short b){
  uint32_t u = ((uint32_t)b) << 16;
  return __builtin_bit_cast(float, u);
}
__device__ __forceinline__ f32x16 mfma16(bf16x8 a, bf16x8 b, f32x16 c){
  return __builtin_amdgcn_mfma_f32_32x32x16_bf16(a, b, c, 0, 0, 0);
}

// Flat-GEMM pre-pass. kappa = i*128 + c. kappa-step gs (16 kappa each):
//   gs < 1024 : i = gs>>3, c-block = (gs&7)*16.  gs 1024..1031: bias steps.
// Layout (byte) = gs*4096 + f*1024 + lg*512 + l31*16 + j*2, holding
// B elem (k = lg*8+j, p = f*32+l31):  W[(i*128+p)*128 + c0+k]  (or bias[ib*128+p]).
// This makes stage (one gload_lds dwordx4 per thread, linear) AND the per-frag
// ds_read_b128 both conflict-free with zero runtime permutation.
__global__ void prep_wb5(const float* __restrict__ W, const float* __restrict__ bias,
                         unsigned short* __restrict__ Wb5){
  int e = blockIdx.x * 256 + threadIdx.x;     // ushort index
  if (e >= 1032 * 2048) return;
  int j = e & 7, l = (e >> 3) & 63, f = (e >> 9) & 3, gs = e >> 11;
  int p = f * 32 + (l & 31);
  int k = ((l >> 5) << 3) + j;
  float v;
  if (gs < 1024){
    int i = gs >> 3, c = ((gs & 7) << 4) + k;
    v = W[(size_t)i * 16384 + p * 128 + c];
  } else {
    int ib = ((gs - 1024) << 4) + k;
    v = bias[ib * 128 + p];
  }
  Wb5[e] = f2bf(v);
}

// dynmlp (flat GEMM): grid 512 = 128 token-tiles(128t) x 4 K-quarters.
// WG 512thr = 8 waves = 4 t-tiles(32t) x 2 p-halves(64p, F=2).  acc = 2 x f32x16.
// X[t,kappa] generated in regs (img*loc, bf16); W' staged in LDS (shared by all
// waves): 4-slot ring of 8KB step-pairs, 1 global_load_lds/thread/phase,
// vmcnt(1) + raw s_barrier per phase (never vmcnt(0) in-loop).  2 WGs/CU,
// 16 waves/CU, 4 waves/SIMD -- the occupancy the factorized datapath blocked.
// LDS: [0,32K) ring, [32K,64K) loc tiles (4 x 8KB, [16 cq][32 t][8 bf16]).
__global__ __launch_bounds__(512, 2)
void dynmlp(const float* __restrict__ img, const float* __restrict__ loc,
            const unsigned short* __restrict__ Wb5, unsigned short* __restrict__ part){
  __shared__ __align__(16) char smem[65536];
  unsigned short* ldsLoc = (unsigned short*)(smem + 32768);

  const int b = blockIdx.x;
  const int q = b & 3, tb = b >> 2;           // XCD b&7 -> fixed quarter b&3
  const int tid = threadIdx.x, lane = tid & 63, wv = tid >> 6;
  const int tIdx = wv >> 1, pH = wv & 1;
  const int l31 = lane & 31, lg = lane >> 5;
  const int t0 = tb * 128;
  const int tw = t0 + tIdx * 32;
  const int fb = pH * 2;                      // this wave's first p-frag

  const char* stageSrc = (const char*)Wb5 + (size_t)q * 1048576 + tid * 16;

  #define STAGEP(P, SLOT) __builtin_amdgcn_global_load_lds( \
      (const AS1 uint32_t*)(stageSrc + (size_t)(P) * 8192), \
      (AS3 uint32_t*)(smem + (SLOT) * 8192 + tid * 16), 16, 0, 0)

  STAGEP(0, 0); STAGEP(1, 1);

  // ---- loc tile -> LDS bf16, [t-tile][cq 0..15][t31 0..31][8] ----
  #pragma unroll
  for (int v = 0; v < 8; ++v){
    int eidx = v * 2048 + tid * 4;
    int t = eidx >> 7, c = eidx & 127;
    float4 f = *(const float4*)&loc[(size_t)(t0 + t) * 128 + c];
    us4 w = {f2bf(f.x), f2bf(f.y), f2bf(f.z), f2bf(f.w)};
    *(us4*)&ldsLoc[(t >> 5) * 4096 + (((c >> 3) * 32 + (t & 31)) << 3) + (c & 7)] = w;
  }

  f32x16 acc[2];
  #pragma unroll
  for (int f = 0; f < 2; ++f)
    #pragma unroll
    for (int r = 0; r < 16; ++r) acc[f][r] = 0.0f;

  const float* imgP = img + (size_t)(tw + l31) * 128 + q * 32;
  const unsigned short* locW = ldsLoc + tIdx * 4096 + l31 * 8;

  __syncthreads();   // loc + stage pairs 0,1 ready (full drain once is fine)

  // consume one kappa-step: A generated (img*loc), B from LDS ring, C=acc direct
  #define CONSUME(SLOT, SPAR, CS, SV) do { \
    const char* bp = smem + (SLOT) * 8192 + (SPAR) * 4096; \
    u32x4 B0 = *(const u32x4*)(bp + (fb) * 1024 + lg * 512 + l31 * 16); \
    u32x4 B1 = *(const u32x4*)(bp + (fb + 1) * 1024 + lg * 512 + l31 * 16); \
    bf16x8 lv = *(const bf16x8*)(locW + (CS) * 512 + lg * 256); \
    bf16x8 av; \
    _Pragma("unroll") \
    for (int j = 0; j < 8; ++j) av[j] = (__bf16)((SV) * (float)lv[j]); \
    acc[0] = mfma16(av, __builtin_bit_cast(bf16x8, B0), acc[0]); \
    acc[1] = mfma16(av, __builtin_bit_cast(bf16x8, B1), acc[1]); \
  } while (0)

  // one phase = stage pair PP+2, counted wait, barrier, consume pair PP (2 steps)
  #define PH(PP, C, SVC) \
    STAGEP((PP) + 2, ((C) + 2) & 3); \
    asm volatile("s_waitcnt vmcnt(1)" ::: "memory"); \
    __builtin_amdgcn_s_barrier(); \
    CONSUME(((C) & 3), 0, (((C) & 3) << 1),     SVC); \
    CONSUME(((C) & 3), 1, (((C) & 3) << 1) + 1, SVC);

  for (int iq = 0; iq < 8; ++iq){            // 4 i-values per iq, 16 phases
    float4 sv4 = *(const float4*)(imgP + iq * 4);
    int PB = iq * 16;                         // PB % 4 == 0 -> slots static
    PH(PB + 0,  0,  sv4.x) PH(PB + 1,  1,  sv4.x)
    PH(PB + 2,  2,  sv4.x) PH(PB + 3,  3,  sv4.x)
    PH(PB + 4,  4,  sv4.y) PH(PB + 5,  5,  sv4.y)
    PH(PB + 6,  6,  sv4.y) PH(PB + 7,  7,  sv4.y)
    PH(PB + 8,  8,  sv4.z) PH(PB + 9,  9,  sv4.z)
    PH(PB + 10, 10, sv4.z) PH(PB + 11, 11, sv4.z)
    PH(PB + 12, 12, sv4.w) PH(PB + 13, 13, sv4.w)
    PH(PB + 14, 14, sv4.w) PH(PB + 15, 15, sv4.w)
  }

  // ---- bias steps (q==0): A = img directly, B from Wb5 via registers ----
  if (q == 0){
    #pragma unroll
    for (int sb = 0; sb < 8; ++sb){
      const char* bp = (const char*)Wb5 + (size_t)(1024 + sb) * 4096;
      u32x4 B0 = *(const u32x4*)(bp + fb * 1024 + lg * 512 + l31 * 16);
      u32x4 B1 = *(const u32x4*)(bp + (fb + 1) * 1024 + lg * 512 + l31 * 16);
      const float* ib = img + (size_t)(tw + l31) * 128 + sb * 16 + lg * 8;
      float4 x = *(const float4*)ib;
      float4 y = *(const float4*)(ib + 4);
      bf16x8 av;
      av[0] = (__bf16)x.x; av[1] = (__bf16)x.y; av[2] = (__bf16)x.z; av[3] = (__bf16)x.w;
      av[4] = (__bf16)y.x; av[5] = (__bf16)y.y; av[6] = (__bf16)y.z; av[7] = (__bf16)y.w;
      acc[0] = mfma16(av, __builtin_bit_cast(bf16x8, B0), acc[0]);
      acc[1] = mfma16(av, __builtin_bit_cast(bf16x8, B1), acc[1]);
    }
  }

  // ---- epilogue: direct bf16 partial stores (D col = p -> coalesced) ----
  // C/D: col = l31 (p within tile), row = (r&3) + 8*(r>>2) + 4*lg (t within tile)
  unsigned short* dst = part + (size_t)q * 2097152;
  #pragma unroll
  for (int f = 0; f < 2; ++f)
    #pragma unroll
    for (int r = 0; r < 16; ++r){
      int t = tw + (r & 3) + 8 * (r >> 2) + 4 * lg;
      dst[(size_t)t * 128 + (fb + f) * 32 + l31] = f2bf(acc[f][r]);
    }
}

// LN kernel: y = sum of 4 bf16 partials, LayerNorm + ReLU. grid 256 x 512 thr.
__global__ __launch_bounds__(512)
void lnk(const unsigned short* __restrict__ part, const float* __restrict__ gamma,
         const float* __restrict__ beta, float* __restrict__ out){
  const int tid = threadIdx.x, lane = tid & 63, wv = tid >> 6;
  const unsigned short* p0 = part;
  const unsigned short* p1 = part + (size_t)16384 * 128;
  const unsigned short* p2 = part + (size_t)2 * 16384 * 128;
  const unsigned short* p3 = part + (size_t)3 * 16384 * 128;
  float g0  = gamma[lane], g1 = gamma[lane + 64];
  float be0 = beta[lane],  be1 = beta[lane + 64];
  int tb = blockIdx.x * 64 + wv * 8;
  #pragma unroll 1
  for (int k = 0; k < 8; ++k){
    size_t t = tb + k;
    size_t i0 = t * 128 + lane, i1 = i0 + 64;
    float y0 = bf2f(p0[i0]) + bf2f(p1[i0]) + bf2f(p2[i0]) + bf2f(p3[i0]);
    float y1 = bf2f(p0[i1]) + bf2f(p1[i1]) + bf2f(p2[i1]) + bf2f(p3[i1]);
    float s = y0 + y1, sq = y0 * y0 + y1 * y1;
    #pragma unroll
    for (int m = 32; m >= 1; m >>= 1){
      s  += __shfl_xor(s, m, 64);
      sq += __shfl_xor(sq, m, 64);
    }
    float mean = s * (1.0f / 128.0f);
    float var  = sq * (1.0f / 128.0f) - mean * mean;
    float rs   = rsqrtf(var + 1e-5f);
    float o0 = fmaxf((y0 - mean) * rs * g0 + be0, 0.0f);
    float o1 = fmaxf((y1 - mean) * rs * g1 + be1, 0.0f);
    out[t * 128 + lane]      = o0;
    out[t * 128 + 64 + lane] = o1;
  }
}

extern "C" void kernel_launch(void* const* d_in, const int* in_sizes, int n_in,
                              void* d_out, int out_size, void* d_ws, size_t ws_size,
                              hipStream_t stream){
  const float* img   = (const float*)d_in[0];
  const float* loc   = (const float*)d_in[1];
  const float* W     = (const float*)d_in[2];
  const float* bias  = (const float*)d_in[3];
  const float* gamma = (const float*)d_in[4];
  const float* beta  = (const float*)d_in[5];
  float* out = (float*)d_out;
  unsigned short* Wb5  = (unsigned short*)d_ws;                    // 1032*4096 = 4,227,072 B
  unsigned short* part = (unsigned short*)((char*)d_ws + 4227072); // 4 x 16384 x 128 bf16

  prep_wb5<<<8256, 256, 0, stream>>>(W, bias, Wb5);
  dynmlp<<<512, 512, 0, stream>>>(img, loc, Wb5, part);
  lnk<<<256, 512, 0, stream>>>(part, gamma, beta, out);
}